// Round 6
// baseline (193.024 us; speedup 1.0000x reference)
//
#include <hip/hip_runtime.h>
#include <math.h>

#define T_ 768
#define TD (T_*64)
#define EPSF 1e-8f
#define NBLK 48

typedef __attribute__((ext_vector_type(8))) short short8;
typedef __attribute__((ext_vector_type(4))) float f32x4;

__device__ __forceinline__ float wave_sum64(float v) {
#pragma unroll
  for (int m = 32; m >= 1; m >>= 1) v += __shfl_xor(v, m, 64);
  return v;
}
__device__ __forceinline__ float wave_max64(float v) {
#pragma unroll
  for (int m = 32; m >= 1; m >>= 1) v = fmaxf(v, __shfl_xor(v, m, 64));
  return v;
}
__device__ __forceinline__ float sigmoidf_(float x) { return 1.0f / (1.0f + expf(-x)); }

__device__ __forceinline__ unsigned short f2bf(float x) {
  unsigned int u = __float_as_uint(x);
  u += 0x7fffu + ((u >> 16) & 1u);        // RNE
  return (unsigned short)(u >> 16);
}

// acos(x), x in [0,1): sqrt(1-x)*poly3, |err|<=6.7e-5 (A-S 4.4.45)
__device__ __forceinline__ float acos_pos(float x) {
  float s = sqrtf(fmaxf(1.0f - x, 0.0f));
  return s * (1.5707288f + x * (-0.2121144f + x * (0.0742610f + x * (-0.0187293f))));
}

// simplex proj + renorm; feature row f=[sqrt(p), sqrt(eps/2)/sqrt(p)] bf16
__device__ __forceinline__ void feat_bf(float v, int row, int lane,
                                        unsigned short* Fb) {
  float sp = fmaxf(v, 0.0f) + log1pf(expf(-fabsf(v)));
  float s = wave_sum64(sp);
  float p1 = fmaxf(sp / (s + EPSF), EPSF);
  float s2 = wave_sum64(p1);
  float p = p1 / (s2 + EPSF);
  Fb[row * 128 + lane] = f2bf(sqrtf(p));
  Fb[row * 128 + 64 + lane] = f2bf(sqrtf(5e-9f / p));
}

// device-scope grid barrier; one counter per use, zeroed by memset each launch.
// All NBLK blocks are co-resident (1 block/CU, 48 <= 256 CUs) => no deadlock.
__device__ __forceinline__ void grid_sync(unsigned* cnt) {
  __syncthreads();
  if (threadIdx.x == 0) {
    __threadfence();   // agent release: write back L2 so other XCDs can see
    __hip_atomic_fetch_add(cnt, 1u, __ATOMIC_ACQ_REL, __HIP_MEMORY_SCOPE_AGENT);
    while (__hip_atomic_load(cnt, __ATOMIC_ACQUIRE, __HIP_MEMORY_SCOPE_AGENT) <
           (unsigned)NBLK)
      __builtin_amdgcn_s_sleep(2);
    __threadfence();   // agent acquire: invalidate L2 so plain loads are fresh
  }
  __syncthreads();
}

__global__ void __launch_bounds__(1024)
mega_kernel(const float* __restrict__ bseq, const float* __restrict__ basin_coords,
            const float* __restrict__ temp_w, const float* __restrict__ temp_b,
            const float* __restrict__ rs_layers, const float* __restrict__ fb_w,
            const float* __restrict__ fb_b,
            const float* __restrict__ w1, const float* __restrict__ b1,
            const float* __restrict__ w2, const float* __restrict__ b2,
            const float* __restrict__ uw, const float* __restrict__ ub,
            const float* __restrict__ res_scale, float* outp,
            float* xA, float* xB, float* prevb, float* fbwT,
            float* poolPart, float* temps, unsigned* bars,
            unsigned short* Fb0, unsigned short* Fb1,
            unsigned short* XT0, unsigned short* XT1) {
  __shared__ __align__(16) float lg[16][776];          // logits
  __shared__ __align__(16) unsigned short Pl[16][776]; // P bf16
  __shared__ __align__(16) float pvp[4][16][68];       // PV K-quarter partials
  __shared__ __align__(16) float xs[16][64];
  __shared__ __align__(16) float ps_s[16][64];
  __shared__ float pooled[64], h1s[32], aggs[64], bnew[64];

  int tid = threadIdx.x, w = tid >> 6, l = tid & 63;
  int lr = l & 15, lk = l >> 4;
  int b = blockIdx.x, i0 = b * 16;

  // ---- phase A: features(bseq)+XT, fb_w transpose, pass-0 temps ----
  {
    int row = i0 + w;
    float v = bseq[row * 64 + l];
    feat_bf(v, row, l, Fb0);
    XT0[l * 768 + row] = f2bf(v);
    int idx = b * 1024 + tid;                 // 48*1024 >= 32768
    if (idx < 32768) {
      int ll = idx >> 13, r = idx & 8191, d = r >> 7, k = r & 127;
      fbwT[ll * 8192 + k * 64 + d] = fb_w[ll * 8192 + d * 128 + k];
    }
    if (b == 0 && w < 4) {
      float t = basin_coords[l] * temp_w[w * 64 + l];
      t = wave_sum64(t);
      if (l == 0) temps[w] = sigmoidf_(t + temp_b[w]) + 0.5f;
    }
  }
  grid_sync(bars + 0);
  int bar = 1;

#pragma unroll 1
  for (int step = 0; step < 8; step++) {
    int lidx = step & 3;
    const float* xin; float* xout = nullptr;
    const float *WTn = nullptr, *bn = nullptr, *pn = nullptr;
    switch (step) {
      case 0: xin = bseq;           xout = prevb;          break;
      case 1: xin = prevb;          xout = prevb + TD;     break;
      case 2: xin = prevb + TD;     xout = prevb + 2 * TD; break;
      case 3: xin = prevb + 2 * TD; xout = prevb + 3 * TD; break;
      case 4: xin = xA; xout = xB; WTn = fbwT + 8192;  bn = fb_b + 64;  pn = prevb + TD;     break;
      case 5: xin = xB; xout = xA; WTn = fbwT + 16384; bn = fb_b + 128; pn = prevb + 2 * TD; break;
      case 6: xin = xA; xout = xB; WTn = fbwT + 24576; bn = fb_b + 192; pn = prevb + 3 * TD; break;
      default: xin = xB; break;     // step 7 -> final out
    }
    const unsigned short* Fbi = (step & 1) ? Fb1 : Fb0;
    const unsigned short* XTi = (step & 1) ? XT1 : XT0;
    unsigned short* Fbo = (step & 1) ? Fb0 : Fb1;
    unsigned short* XTo = (step & 1) ? XT0 : XT1;

    if (pn) ps_s[w][l] = pn[(i0 + w) * 64 + l];

    // A-frags: lane holds F row i0+lr, k = ks*32 + lk*8 .. +7
    const short8* arow = reinterpret_cast<const short8*>(Fbi + (i0 + lr) * 128);
    short8 afr[4];
#pragma unroll
    for (int ks = 0; ks < 4; ks++) afr[ks] = arow[ks * 4 + lk];
    float inv_t = 1.0f / fmaxf(temps[step], 1e-6f);

    // ---- QK Gram: wave w owns j-tiles w, w+16, w+32 ----
#pragma unroll
    for (int jj = 0; jj < 3; jj++) {
      int jt = w + jj * 16;
      const short8* brow = reinterpret_cast<const short8*>(Fbi + (jt * 16 + lr) * 128);
      f32x4 acc = {0.f, 0.f, 0.f, 0.f};
#pragma unroll
      for (int ks = 0; ks < 4; ks++)
        acc = __builtin_amdgcn_mfma_f32_16x16x32_bf16(afr[ks], brow[ks * 4 + lk], acc, 0, 0, 0);
#pragma unroll
      for (int r = 0; r < 4; r++) {
        float inner = fminf(fmaxf(acc[r], 0.0f), 1.0f - 1e-6f);
        lg[lk * 4 + r][jt * 16 + lr] = -2.0f * acos_pos(inner) * inv_t;
      }
    }
    __syncthreads();

    // ---- softmax: wave w row w ----
    {
      float v[12];
      float m = -1e30f;
#pragma unroll
      for (int q = 0; q < 12; q++) { v[q] = lg[w][l + 64 * q]; m = fmaxf(m, v[q]); }
      m = wave_max64(m);
      float s = 0.f;
#pragma unroll
      for (int q = 0; q < 12; q++) { v[q] = expf(v[q] - m); s += v[q]; }
      s = wave_sum64(s);
      float is = 1.0f / s;
#pragma unroll
      for (int q = 0; q < 12; q++) Pl[w][l + 64 * q] = f2bf(v[q] * is);
    }
    __syncthreads();

    // ---- PV: wave (cg=w&3, kq=w>>2): cols cg*16..+15, K-chunk kq*192 ----
    {
      int cg = w & 3, kq = w >> 2;
      f32x4 pacc = {0.f, 0.f, 0.f, 0.f};
      const short8* xtrow =
          reinterpret_cast<const short8*>(XTi + (cg * 16 + lr) * 768 + kq * 192);
#pragma unroll
      for (int ks = 0; ks < 6; ks++) {
        short8 pa = *reinterpret_cast<const short8*>(&Pl[lr][kq * 192 + ks * 32 + lk * 8]);
        pacc = __builtin_amdgcn_mfma_f32_16x16x32_bf16(pa, xtrow[ks * 4 + lk], pacc, 0, 0, 0);
      }
#pragma unroll
      for (int r = 0; r < 4; r++) pvp[kq][lk * 4 + r][cg * 16 + lr] = pacc[r];
    }
    __syncthreads();

    // ---- residual: wave w row w ----
    {
      float pv = pvp[0][w][l] + pvp[1][w][l] + pvp[2][w][l] + pvp[3][w][l];
      float xi = xin[(i0 + w) * 64 + l];
      float rs = rs_layers[lidx];
      xs[w][l] = xi + rs * (pv - xi);
    }
    __syncthreads();

    // ---- tails ----
    int row = i0 + w;
    float xo = xs[w][l];
    if (step == 7) {
      float sc = 0.01f * res_scale[0];
      outp[row * 64 + l] = xo + sc * (xo - bseq[row * 64 + l]);
    } else if (WTn) {                        // feedback gate for next ref-layer
      float a = bn[l];
#pragma unroll 8
      for (int k = 0; k < 64; k++) a += xs[w][k] * WTn[k * 64 + l];
#pragma unroll 8
      for (int k = 0; k < 64; k++) a += ps_s[w][k] * WTn[(64 + k) * 64 + l];
      float g = sigmoidf_(a);
      float xn = xo * g + ps_s[w][l] * (1.0f - g);
      xout[row * 64 + l] = xn;
      XTo[l * 768 + row] = f2bf(xn);
      feat_bf(xn, row, l, Fbo);
    } else if (step != 3) {
      xout[row * 64 + l] = xo;
      XTo[l * 768 + row] = f2bf(xo);
      feat_bf(xo, row, l, Fbo);
    } else {                                 // step 3: x out + pool partial
      xout[row * 64 + l] = xo;
      if (w == 0) {
        float s = 0.f;
#pragma unroll
        for (int r2 = 0; r2 < 16; r2++) s += xs[r2][l];
        poolPart[b * 64 + l] = s;
      }
    }

    if (step < 7) { grid_sync(bars + bar); bar++; }

    if (step == 3) {
      // ---- compress: gate(pass1,l=0) on all blocks; block 0 MLP+basin+temps ----
      ps_s[w][l] = prevb[(i0 + w) * 64 + l];   // prev0; xs still holds step-3 out
      __syncthreads();
      {
        float a = fb_b[l];
#pragma unroll 8
        for (int k = 0; k < 64; k++) a += xs[w][k] * fbwT[k * 64 + l];
#pragma unroll 8
        for (int k = 0; k < 64; k++) a += ps_s[w][k] * fbwT[(64 + k) * 64 + l];
        float g = sigmoidf_(a);
        float xn = xs[w][l] * g + ps_s[w][l] * (1.0f - g);
        xA[row * 64 + l] = xn;
        XT0[l * 768 + row] = f2bf(xn);
        feat_bf(xn, row, l, Fb0);
      }
      if (b == 0) {
        __syncthreads();
        if (w == 0) {
          float s = 0.f;
          for (int bb = 0; bb < NBLK; bb++) s += poolPart[bb * 64 + l];
          pooled[l] = s * (1.0f / 768.0f);
        }
        __syncthreads();
        if (tid < 32) {
          float h = b1[tid];
          for (int k = 0; k < 64; k++) h += w1[tid * 64 + k] * pooled[k];
          h1s[tid] = tanhf(h);
        }
        __syncthreads();
        if (tid < 64) {
          float h = b2[tid];
          for (int k = 0; k < 32; k++) h += w2[tid * 32 + k] * h1s[k];
          aggs[tid] = tanhf(h);
        }
        __syncthreads();
        if (tid < 64) {
          float g = ub[tid];
          for (int k = 0; k < 64; k++) g += uw[tid * 128 + k] * basin_coords[k];
          for (int k = 0; k < 64; k++) g += uw[tid * 128 + 64 + k] * aggs[k];
          g = sigmoidf_(g);
          bnew[tid] = basin_coords[tid] * (1.0f - g) + aggs[tid] * g;
        }
        __syncthreads();
        if (w < 4) {
          float t = bnew[l] * temp_w[w * 64 + l];
          t = wave_sum64(t);
          if (l == 0) temps[4 + w] = sigmoidf_(t + temp_b[w]) + 0.5f;
        }
      }
      grid_sync(bars + bar); bar++;
    }
  }
}

extern "C" void kernel_launch(void* const* d_in, const int* in_sizes, int n_in,
                              void* d_out, int out_size, void* d_ws, size_t ws_size,
                              hipStream_t stream) {
  const float* bseq         = (const float*)d_in[0];
  const float* basin_coords = (const float*)d_in[1];
  const float* temp_w       = (const float*)d_in[2];
  const float* temp_b       = (const float*)d_in[3];
  const float* rs_layers    = (const float*)d_in[4];
  const float* fb_w         = (const float*)d_in[5];
  const float* fb_b         = (const float*)d_in[6];
  const float* comp_w1      = (const float*)d_in[7];
  const float* comp_b1      = (const float*)d_in[8];
  const float* comp_w2      = (const float*)d_in[9];
  const float* comp_b2      = (const float*)d_in[10];
  const float* upd_w        = (const float*)d_in[11];
  const float* upd_b        = (const float*)d_in[12];
  const float* res_scale    = (const float*)d_in[13];
  float* out = (float*)d_out;

  float* ws = (float*)d_ws;
  float* xA = ws;                         // TD
  float* xB = xA + TD;                    // TD
  float* prevb = xB + TD;                 // 4*TD
  float* fbwT = prevb + 4 * TD;           // 32768
  float* poolPart = fbwT + 32768;         // 48*64 -> pad to 3072
  float* temps = poolPart + 3072;         // 8
  unsigned* bars = (unsigned*)(temps + 8);            // 16 counters
  unsigned short* Fb0 = (unsigned short*)(bars + 16); // 768*128 bf16 (16B-aligned)
  unsigned short* Fb1 = Fb0 + 98304;
  unsigned short* XT0 = Fb1 + 98304;      // 64*768 bf16
  unsigned short* XT1 = XT0 + 49152;

  hipMemsetAsync(bars, 0, 16 * sizeof(unsigned), stream);
  mega_kernel<<<NBLK, 1024, 0, stream>>>(
      bseq, basin_coords, temp_w, temp_b, rs_layers, fb_w, fb_b,
      comp_w1, comp_b1, comp_w2, comp_b2, upd_w, upd_b, res_scale, out,
      xA, xB, prevb, fbwT, poolPart, temps, bars, Fb0, Fb1, XT0, XT1);
}

// Round 7
// 99.141 us; speedup vs baseline: 1.9470x; 1.9470x over previous
//
#include <hip/hip_runtime.h>
#include <math.h>

#define T_ 768
#define TD (T_*64)
#define EPSF 1e-8f

typedef __attribute__((ext_vector_type(8))) short short8;
typedef __attribute__((ext_vector_type(4))) float f32x4;

__device__ __forceinline__ float wave_sum64(float v) {
#pragma unroll
  for (int m = 32; m >= 1; m >>= 1) v += __shfl_xor(v, m, 64);
  return v;
}
__device__ __forceinline__ float sigmoidf_(float x) { return 1.0f / (1.0f + expf(-x)); }

__device__ __forceinline__ unsigned short f2bf(float x) {
  unsigned int u = __float_as_uint(x);
  u += 0x7fffu + ((u >> 16) & 1u);        // RNE
  return (unsigned short)(u >> 16);
}

// acos(x), x in [0,1): sqrt(1-x)*poly3, |err|<=6.7e-5 (A-S 4.4.45)
__device__ __forceinline__ float acos_pos(float x) {
  float s = sqrtf(fmaxf(1.0f - x, 0.0f));
  return s * (1.5707288f + x * (-0.2121144f + x * (0.0742610f + x * (-0.0187293f))));
}

// simplex proj + renorm; feature row f=[sqrt(p), sqrt(eps/2)/sqrt(p)] bf16
__device__ __forceinline__ void feat_bf(float v, int row, int lane,
                                        unsigned short* __restrict__ Fb) {
  float sp = fmaxf(v, 0.0f) + log1pf(expf(-fabsf(v)));
  float s = wave_sum64(sp);
  float p1 = fmaxf(sp / (s + EPSF), EPSF);
  float s2 = wave_sum64(p1);
  float p = p1 / (s2 + EPSF);
  Fb[row * 128 + lane] = f2bf(sqrtf(p));
  Fb[row * 128 + 64 + lane] = f2bf(sqrtf(5e-9f / p));
}

// features(bseq) + XT(bseq) + fb_w transpose + pass-0 temps. grid 192x256.
__global__ void __launch_bounds__(256)
phaseA_kernel(const float* __restrict__ bseq, const float* __restrict__ basin_coords,
              const float* __restrict__ temp_w, const float* __restrict__ temp_b,
              const float* __restrict__ fb_w,
              unsigned short* __restrict__ Fb, unsigned short* __restrict__ XTb,
              float* __restrict__ fbwT, float* __restrict__ temps) {
  int b = blockIdx.x, tid = threadIdx.x, w = tid >> 6, l = tid & 63;
  int row = b * 4 + w;
  float v = bseq[row * 64 + l];
  feat_bf(v, row, l, Fb);
  XTb[l * 768 + row] = f2bf(v);
  if (b < 128) {                          // 128*256 = 4*64*128
    int idx = b * 256 + tid;
    int ll = idx >> 13, r = idx & 8191, d = r >> 7, k = r & 127;
    fbwT[ll * 8192 + k * 64 + d] = fb_w[ll * 8192 + d * 128 + k];
  }
  if (b == 191) {
    float t = basin_coords[l] * temp_w[w * 64 + l];
    t = wave_sum64(t);
    if (l == 0) temps[w] = sigmoidf_(t + temp_b[w]) + 0.5f;
  }
}

// QK Gram (MFMA) -> acos/exp (no-max softmax numerator) -> partial sums
// -> MFMA PV partial. grid 192 = (rowtile 0..47) x (j-chunk 0..3), 256 thr.
__global__ void __launch_bounds__(256)
qkpv_kernel(const unsigned short* __restrict__ Fbi,
            const unsigned short* __restrict__ XTi,
            const float* __restrict__ temps, int tidx,
            float* __restrict__ pvp_g, float* __restrict__ psum_g) {
  __shared__ __align__(16) unsigned short Pl[16][200];   // exp weights bf16
  __shared__ float psumP[4][16];
  int tid = threadIdx.x, w = tid >> 6, l = tid & 63;
  int lr = l & 15, lk = l >> 4;
  int rt = blockIdx.x >> 2, c = blockIdx.x & 3;
  int i0 = rt * 16;

  const short8* arow = reinterpret_cast<const short8*>(Fbi + (i0 + lr) * 128);
  short8 afr[4];
#pragma unroll
  for (int ks = 0; ks < 4; ks++) afr[ks] = arow[ks * 4 + lk];
  float inv_t = 1.0f / fmaxf(temps[tidx], 1e-6f);

  float sp[4] = {0.f, 0.f, 0.f, 0.f};
#pragma unroll
  for (int jj = 0; jj < 3; jj++) {
    int jt = w + jj * 4;                  // local j-tile 0..11
    int jg = c * 12 + jt;                 // global j-tile
    const short8* brow = reinterpret_cast<const short8*>(Fbi + (jg * 16 + lr) * 128);
    f32x4 acc = {0.f, 0.f, 0.f, 0.f};
#pragma unroll
    for (int ks = 0; ks < 4; ks++)
      acc = __builtin_amdgcn_mfma_f32_16x16x32_bf16(afr[ks], brow[ks * 4 + lk], acc, 0, 0, 0);
    // C layout: col = lane&15 (j), row = (lane>>4)*4 + r (i)
#pragma unroll
    for (int r = 0; r < 4; r++) {
      float inner = fminf(fmaxf(acc[r], 0.0f), 1.0f - 1e-6f);
      float e = expf(-2.0f * acos_pos(inner) * inv_t);   // max logit ~ 0: no-max is safe
      Pl[lk * 4 + r][jt * 16 + lr] = f2bf(e);
      sp[r] += e;
    }
  }
  // row-sum partials: reduce over the 16-lane lr group
#pragma unroll
  for (int m = 1; m <= 8; m <<= 1)
#pragma unroll
    for (int r = 0; r < 4; r++) sp[r] += __shfl_xor(sp[r], m, 64);
  if (lr == 0)
#pragma unroll
    for (int r = 0; r < 4; r++) psumP[w][lk * 4 + r] = sp[r];
  __syncthreads();

  // PV partial: wave w -> cols w*16..+15, K = this chunk's 192 j's
  f32x4 pacc = {0.f, 0.f, 0.f, 0.f};
  const short8* xtrow =
      reinterpret_cast<const short8*>(XTi + (w * 16 + lr) * 768 + c * 192);
#pragma unroll
  for (int ks = 0; ks < 6; ks++) {
    short8 pa = *reinterpret_cast<const short8*>(&Pl[lr][ks * 32 + lk * 8]);
    pacc = __builtin_amdgcn_mfma_f32_16x16x32_bf16(pa, xtrow[ks * 4 + lk], pacc, 0, 0, 0);
  }
  float* dst = pvp_g + (blockIdx.x << 10);
#pragma unroll
  for (int r = 0; r < 4; r++) dst[(lk * 4 + r) * 64 + w * 16 + lr] = pacc[r];
  if (tid < 16)
    psum_g[blockIdx.x * 16 + tid] =
        psumP[0][tid] + psumP[1][tid] + psumP[2][tid] + psumP[3][tid];
}

// combine partials -> normalize -> residual -> tail. grid 192 (4 rows each), 256 thr.
// mode 0: plain+feat; 1: step3 (pool + gate(l0) + feat(gated)); 2: pass1 gate+feat; 3: final
__global__ void __launch_bounds__(256)
combine_kernel(const float* __restrict__ pvp_g, const float* __restrict__ psum_g,
               const float* __restrict__ xin, int lidx,
               const float* __restrict__ rs_layers, int mode,
               float* __restrict__ xout,
               unsigned short* __restrict__ Fbo, unsigned short* __restrict__ XTo,
               const float* __restrict__ WT, const float* __restrict__ bb,
               const float* __restrict__ prevX,
               float* __restrict__ gateOut, float* __restrict__ poolPart,
               const float* __restrict__ bseq, const float* __restrict__ res_scale,
               float* __restrict__ outp) {
  __shared__ float xs[4][64], ps[4][64];
  int tid = threadIdx.x, w = tid >> 6, l = tid & 63;
  int bid = blockIdx.x;
  int rt = bid >> 2, row16 = (bid & 3) * 4 + w;
  int grow = bid * 4 + w;

  float pv = 0.f, s = 0.f;
#pragma unroll
  for (int c = 0; c < 4; c++) {
    pv += pvp_g[((rt * 4 + c) << 10) + row16 * 64 + l];
    s += psum_g[(rt * 4 + c) * 16 + row16];
  }
  float attn = pv / s;
  float xi = xin[grow * 64 + l];
  float rs = rs_layers[lidx];
  float xo = xi + rs * (attn - xi);
  xs[w][l] = xo;
  if (mode == 1 || mode == 2) ps[w][l] = prevX[grow * 64 + l];
  __syncthreads();

  if (mode == 3) {
    outp[grow * 64 + l] = xo + 0.01f * res_scale[0] * (xo - bseq[grow * 64 + l]);
    return;
  }
  if (mode == 0) {
    xout[grow * 64 + l] = xo;
    XTo[l * 768 + grow] = f2bf(xo);
    feat_bf(xo, grow, l, Fbo);
    return;
  }
  // gate: a = bb + [x, prev] . W^T   (WT is (128,64) k-major)
  float a = bb[l];
#pragma unroll 8
  for (int k = 0; k < 64; k++) a += xs[w][k] * WT[k * 64 + l];
#pragma unroll 8
  for (int k = 0; k < 64; k++) a += ps[w][k] * WT[(64 + k) * 64 + l];
  float g = sigmoidf_(a);
  float xn = xo * g + ps[w][l] * (1.0f - g);
  if (mode == 1) {
    xout[grow * 64 + l] = xo;             // prevb3 (pass0 l3 out)
    gateOut[grow * 64 + l] = xn;          // pass1 l0 input
    XTo[l * 768 + grow] = f2bf(xn);
    feat_bf(xn, grow, l, Fbo);
    if (w == 0)
      poolPart[bid * 64 + l] = xs[0][l] + xs[1][l] + xs[2][l] + xs[3][l];
  } else {
    xout[grow * 64 + l] = xn;
    XTo[l * 768 + grow] = f2bf(xn);
    feat_bf(xn, grow, l, Fbo);
  }
}

// pool reduce -> MLP -> basin update -> temps[4..7]. 1 block, 256 thr.
__global__ void __launch_bounds__(256)
mlp_kernel(const float* __restrict__ poolPart, const float* __restrict__ basin_coords,
           const float* __restrict__ temp_w, const float* __restrict__ temp_b,
           const float* __restrict__ w1, const float* __restrict__ b1,
           const float* __restrict__ w2, const float* __restrict__ b2,
           const float* __restrict__ uw, const float* __restrict__ ub,
           float* __restrict__ temps) {
  __shared__ float part4[4][64];
  __shared__ float pooled[64], h1s[32], aggs[64], bnew[64];
  int tid = threadIdx.x, w = tid >> 6, l = tid & 63;
  {
    float s = 0.f;
    for (int bb = w * 48; bb < w * 48 + 48; bb++) s += poolPart[bb * 64 + l];
    part4[w][l] = s;
  }
  __syncthreads();
  if (tid < 64)
    pooled[tid] = (part4[0][tid] + part4[1][tid] + part4[2][tid] + part4[3][tid]) *
                  (1.0f / 768.0f);
  __syncthreads();
  if (tid < 32) {
    float h = b1[tid];
    for (int k = 0; k < 64; k++) h += w1[tid * 64 + k] * pooled[k];
    h1s[tid] = tanhf(h);
  }
  __syncthreads();
  if (tid < 64) {
    float h = b2[tid];
    for (int k = 0; k < 32; k++) h += w2[tid * 32 + k] * h1s[k];
    aggs[tid] = tanhf(h);
  }
  __syncthreads();
  if (tid < 64) {
    float g = ub[tid];
    for (int k = 0; k < 64; k++) g += uw[tid * 128 + k] * basin_coords[k];
    for (int k = 0; k < 64; k++) g += uw[tid * 128 + 64 + k] * aggs[k];
    g = sigmoidf_(g);
    bnew[tid] = basin_coords[tid] * (1.0f - g) + aggs[tid] * g;
  }
  __syncthreads();
  {
    float t = bnew[l] * temp_w[w * 64 + l];
    t = wave_sum64(t);
    if (l == 0) temps[4 + w] = sigmoidf_(t + temp_b[w]) + 0.5f;
  }
}

extern "C" void kernel_launch(void* const* d_in, const int* in_sizes, int n_in,
                              void* d_out, int out_size, void* d_ws, size_t ws_size,
                              hipStream_t stream) {
  const float* bseq         = (const float*)d_in[0];
  const float* basin_coords = (const float*)d_in[1];
  const float* temp_w       = (const float*)d_in[2];
  const float* temp_b       = (const float*)d_in[3];
  const float* rs_layers    = (const float*)d_in[4];
  const float* fb_w         = (const float*)d_in[5];
  const float* fb_b         = (const float*)d_in[6];
  const float* comp_w1      = (const float*)d_in[7];
  const float* comp_b1      = (const float*)d_in[8];
  const float* comp_w2      = (const float*)d_in[9];
  const float* comp_b2      = (const float*)d_in[10];
  const float* upd_w        = (const float*)d_in[11];
  const float* upd_b        = (const float*)d_in[12];
  const float* res_scale    = (const float*)d_in[13];
  float* out = (float*)d_out;

  float* ws = (float*)d_ws;
  float* xA       = ws;                    // 49152
  float* xB       = xA + TD;               // 49152
  float* prevb    = xB + TD;               // 4*49152
  float* fbwT     = prevb + 4 * TD;        // 32768
  float* poolPart = fbwT + 32768;          // 192*64
  float* psum_g   = poolPart + 12288;      // 192*16
  float* pvp_g    = psum_g + 3072;         // 192*1024
  float* temps    = pvp_g + 196608;        // 8 (pad 16)
  unsigned short* Fb0 = (unsigned short*)(temps + 16);
  unsigned short* Fb1 = Fb0 + 98304;
  unsigned short* XT0 = Fb1 + 98304;
  unsigned short* XT1 = XT0 + 49152;

  // ---- pass 0 ----
  phaseA_kernel<<<192, 256, 0, stream>>>(bseq, basin_coords, temp_w, temp_b, fb_w,
                                         Fb0, XT0, fbwT, temps);
  qkpv_kernel<<<192, 256, 0, stream>>>(Fb0, XT0, temps, 0, pvp_g, psum_g);
  combine_kernel<<<192, 256, 0, stream>>>(pvp_g, psum_g, bseq, 0, rs_layers, 0,
                                          prevb, Fb1, XT1, nullptr, nullptr, nullptr,
                                          nullptr, nullptr, nullptr, nullptr, nullptr);
  qkpv_kernel<<<192, 256, 0, stream>>>(Fb1, XT1, temps, 1, pvp_g, psum_g);
  combine_kernel<<<192, 256, 0, stream>>>(pvp_g, psum_g, prevb, 1, rs_layers, 0,
                                          prevb + TD, Fb0, XT0, nullptr, nullptr, nullptr,
                                          nullptr, nullptr, nullptr, nullptr, nullptr);
  qkpv_kernel<<<192, 256, 0, stream>>>(Fb0, XT0, temps, 2, pvp_g, psum_g);
  combine_kernel<<<192, 256, 0, stream>>>(pvp_g, psum_g, prevb + TD, 2, rs_layers, 0,
                                          prevb + 2 * TD, Fb1, XT1, nullptr, nullptr, nullptr,
                                          nullptr, nullptr, nullptr, nullptr, nullptr);
  qkpv_kernel<<<192, 256, 0, stream>>>(Fb1, XT1, temps, 3, pvp_g, psum_g);
  // step3: residual -> prevb3; pool; gate(l0) -> xA; feat(xA) -> Fb0/XT0
  combine_kernel<<<192, 256, 0, stream>>>(pvp_g, psum_g, prevb + 2 * TD, 3, rs_layers, 1,
                                          prevb + 3 * TD, Fb0, XT0,
                                          fbwT, fb_b, prevb,
                                          xA, poolPart, nullptr, nullptr, nullptr);
  mlp_kernel<<<1, 256, 0, stream>>>(poolPart, basin_coords, temp_w, temp_b,
                                    comp_w1, comp_b1, comp_w2, comp_b2,
                                    upd_w, upd_b, temps);
  // ---- pass 1 ----
  qkpv_kernel<<<192, 256, 0, stream>>>(Fb0, XT0, temps, 4, pvp_g, psum_g);
  combine_kernel<<<192, 256, 0, stream>>>(pvp_g, psum_g, xA, 0, rs_layers, 2,
                                          xB, Fb1, XT1,
                                          fbwT + 8192, fb_b + 64, prevb + TD,
                                          nullptr, nullptr, nullptr, nullptr, nullptr);
  qkpv_kernel<<<192, 256, 0, stream>>>(Fb1, XT1, temps, 5, pvp_g, psum_g);
  combine_kernel<<<192, 256, 0, stream>>>(pvp_g, psum_g, xB, 1, rs_layers, 2,
                                          xA, Fb0, XT0,
                                          fbwT + 16384, fb_b + 128, prevb + 2 * TD,
                                          nullptr, nullptr, nullptr, nullptr, nullptr);
  qkpv_kernel<<<192, 256, 0, stream>>>(Fb0, XT0, temps, 6, pvp_g, psum_g);
  combine_kernel<<<192, 256, 0, stream>>>(pvp_g, psum_g, xA, 2, rs_layers, 2,
                                          xB, Fb1, XT1,
                                          fbwT + 24576, fb_b + 192, prevb + 3 * TD,
                                          nullptr, nullptr, nullptr, nullptr, nullptr);
  qkpv_kernel<<<192, 256, 0, stream>>>(Fb1, XT1, temps, 7, pvp_g, psum_g);
  combine_kernel<<<192, 256, 0, stream>>>(pvp_g, psum_g, xB, 3, rs_layers, 3,
                                          nullptr, nullptr, nullptr, nullptr, nullptr, nullptr,
                                          nullptr, nullptr, bseq, res_scale, out);
}